// Round 2
// baseline (147.440 us; speedup 1.0000x reference)
//
#include <hip/hip_runtime.h>

#pragma clang fp contract(off)

#define B_SZ 16
#define P_SZ 16384
#define C_SZ 80
#define T_SZ 32

// ws layout:
// [0, 4096):      unsigned long long keys[B_SZ*T_SZ]  (per-truth argmax, packed)
// [4096, +32):    Accums
struct Accums { double sum_l; double sum_c; unsigned n_pos; unsigned n_ign; };

__device__ __forceinline__ float iou_ref(float ax0, float ay0, float ax1, float ay1, float aarea,
                                         float bx0, float by0, float bx1, float by1, float barea) {
    float lx = fmaxf(ax0, bx0), ly = fmaxf(ay0, by0);
    float rx = fminf(ax1, bx1), ry = fminf(ay1, by1);
    float w = fmaxf(rx - lx, 0.0f), h = fmaxf(ry - ly, 0.0f);
    float inter = w * h;
    float denom = (aarea + barea) - inter;
    return inter / denom;
}

// ---------------- Kernel A: per-truth argmax over all priors ----------------
__global__ __launch_bounds__(256) void match_kernel(const float* __restrict__ priors,
                                                    const float* __restrict__ targets,
                                                    unsigned long long* __restrict__ keys) {
    const int b = blockIdx.y;
    const int p0 = blockIdx.x * 1024;
    const int tid = threadIdx.x;

    __shared__ float tx0[T_SZ], ty0[T_SZ], tx1[T_SZ], ty1[T_SZ], tar[T_SZ];
    __shared__ float red_ov[4][T_SZ];
    __shared__ int   red_ix[4][T_SZ];

    if (tid < T_SZ) {
        const float* tp = targets + (b * T_SZ + tid) * 5;
        float x0 = tp[0], y0 = tp[1], x1 = tp[2], y1 = tp[3];
        tx0[tid] = x0; ty0[tid] = y0; tx1[tid] = x1; ty1[tid] = y1;
        tar[tid] = (x1 - x0) * (y1 - y0);
    }
    __syncthreads();

    float bov[T_SZ];
    int   bpi[T_SZ];
#pragma unroll
    for (int t = 0; t < T_SZ; ++t) { bov[t] = -1.0f; bpi[t] = 0x7FFFFFFF; }

#pragma unroll
    for (int i = 0; i < 4; ++i) {
        int p = p0 + tid + i * 256;
        float4 pr = reinterpret_cast<const float4*>(priors)[p];
        float px0 = pr.x - pr.z * 0.5f, py0 = pr.y - pr.w * 0.5f;
        float px1 = pr.x + pr.z * 0.5f, py1 = pr.y + pr.w * 0.5f;
        float parea = (px1 - px0) * (py1 - py0);
#pragma unroll
        for (int t = 0; t < T_SZ; ++t) {
            float iou = iou_ref(tx0[t], ty0[t], tx1[t], ty1[t], tar[t], px0, py0, px1, py1, parea);
            if (iou > bov[t]) { bov[t] = iou; bpi[t] = p; }  // ascending p -> first-index tie-break
        }
    }

    const int lane = tid & 63, wid = tid >> 6;
#pragma unroll
    for (int t = 0; t < T_SZ; ++t) {
        float v = bov[t]; int ix = bpi[t];
#pragma unroll
        for (int off = 32; off > 0; off >>= 1) {
            float v2 = __shfl_down(v, off, 64);
            int   i2 = __shfl_down(ix, off, 64);
            if (v2 > v || (v2 == v && i2 < ix)) { v = v2; ix = i2; }
        }
        if (lane == 0) { red_ov[wid][t] = v; red_ix[wid][t] = ix; }
    }
    __syncthreads();

    if (tid < T_SZ) {
        float v = red_ov[0][tid]; int ix = red_ix[0][tid];
#pragma unroll
        for (int w = 1; w < 4; ++w) {
            float v2 = red_ov[w][tid]; int i2 = red_ix[w][tid];
            if (v2 > v || (v2 == v && i2 < ix)) { v = v2; ix = i2; }
        }
        // pack: higher iou wins; tie -> smaller prior index (via ~idx)
        unsigned long long key = (((unsigned long long)__float_as_uint(v)) << 32)
                               | (unsigned long long)(0xFFFFFFFFu - (unsigned)ix);
        atomicMax(keys + b * T_SZ + tid, key);
    }
}

// ---------------- balanced L1 ----------------
__device__ __forceinline__ float bl1(float pred, float target) {
    const float bC   = (float)19.085536923187668;            // e^3 - 1
    const float aob  = (float)(0.5 / 19.085536923187668);    // alpha/b
    const float cL   = (float)(1.5 / 19.085536923187668 - 0.055); // gamma/b - alpha*beta
    float d = fabsf(pred - target);
    if (d < 0.11f) {
        return aob * (bC * d + 1.0f) * __logf(bC * d / 0.11f + 1.0f) - 0.5f * d;
    }
    return 1.5f * d + cL;
}

// ---------------- focal (t in {0,1}, gamma = 1) ----------------
__device__ __forceinline__ float focal(float x, bool isT) {
    float u  = __expf(-fabsf(x));
    float L  = __logf(1.0f + u);
    float q  = __builtin_amdgcn_rcpf(1.0f + u);
    float p  = (x >= 0.0f) ? q : 1.0f - q;   // sigmoid(x)
    float xp = fmaxf(x, 0.0f);
    float xn = xp - x;                        // max(-x, 0)
    // t=1: 0.25*(1-p)*softplus(-x) ; t=0: 0.75*p*softplus(x)
    return isT ? 0.25f * (1.0f - p) * (xn + L) : 0.75f * p * (xp + L);
}

// ---------------- Kernel B: losses ----------------
__global__ __launch_bounds__(256) void loss_kernel(const float* __restrict__ loc_data,
                                                   const float* __restrict__ conf_data,
                                                   const float* __restrict__ priors,
                                                   const float* __restrict__ targets,
                                                   const unsigned long long* __restrict__ keys,
                                                   Accums* __restrict__ acc) {
    const int b = blockIdx.y;
    const int p0 = blockIdx.x * 128;
    const int tid = threadIdx.x;

    __shared__ float tx0[T_SZ], ty0[T_SZ], tx1[T_SZ], ty1[T_SZ], tar[T_SZ];
    __shared__ int tlab[T_SZ], bp[T_SZ];
    __shared__ unsigned char flag_s[128];
    __shared__ unsigned char tcls_s[128];
    __shared__ float rf_l[4], rf_c[4];
    __shared__ int ri_p[4], ri_i[4];

    if (tid < T_SZ) {
        const float* tp = targets + (b * T_SZ + tid) * 5;
        float x0 = tp[0], y0 = tp[1], x1 = tp[2], y1 = tp[3];
        tx0[tid] = x0; ty0[tid] = y0; tx1[tid] = x1; ty1[tid] = y1;
        tar[tid] = (x1 - x0) * (y1 - y0);
        tlab[tid] = (int)tp[4];
        unsigned long long k = keys[b * T_SZ + tid];
        bp[tid] = (int)(0xFFFFFFFFu - (unsigned)(k & 0xFFFFFFFFull));
    }
    __syncthreads();

    float sum_l = 0.0f, sum_c = 0.0f;
    int pos_c = 0, ign_c = 0;

    if (tid < 128) {
        int p = p0 + tid;
        float4 pr = reinterpret_cast<const float4*>(priors)[p];
        float px0 = pr.x - pr.z * 0.5f, py0 = pr.y - pr.w * 0.5f;
        float px1 = pr.x + pr.z * 0.5f, py1 = pr.y + pr.w * 0.5f;
        float parea = (px1 - px0) * (py1 - py0);

        float ov = -1.0f; int idx = 0;
#pragma unroll
        for (int t = 0; t < T_SZ; ++t) {
            float iou = iou_ref(tx0[t], ty0[t], tx1[t], ty1[t], tar[t], px0, py0, px1, py1, parea);
            if (iou > ov) { ov = iou; idx = t; }   // first-index tie-break
        }
        // override: ascending t, last write wins (matches .at[].set)
#pragma unroll
        for (int t = 0; t < T_SZ; ++t) if (bp[t] == p) { ov = 2.0f; idx = t; }

        int fl = (ov >= 0.5f) ? 1 : ((ov >= 0.4f) ? 2 : 0);
        flag_s[tid] = (unsigned char)fl;
        tcls_s[tid] = (unsigned char)tlab[idx];

        if (fl == 1) {
            pos_c = 1;
            float4 ld = reinterpret_cast<const float4*>(loc_data)[b * P_SZ + p];
            float mx0 = tx0[idx], my0 = ty0[idx], mx1 = tx1[idx], my1 = ty1[idx];
            float gx = ((mx0 + mx1) * 0.5f - pr.x) / (0.1f * pr.z);
            float gy = ((my0 + my1) * 0.5f - pr.y) / (0.1f * pr.w);
            float gw = __logf((mx1 - mx0) / pr.z) / 0.2f;
            float gh = __logf((my1 - my0) / pr.w) / 0.2f;
            sum_l = bl1(ld.x, gx) + bl1(ld.y, gy) + bl1(ld.z, gw) + bl1(ld.w, gh);
        } else if (fl == 2) {
            ign_c = 1;
        }
    }
    __syncthreads();

    // conf stream: 128 priors * 80 ch = 10240 floats = 2560 float4; coalesced
    const float4* cbase = reinterpret_cast<const float4*>(conf_data + ((size_t)(b * P_SZ + p0)) * C_SZ);
#pragma unroll
    for (int it = 0; it < 10; ++it) {
        int j = tid + it * 256;
        float4 v = cbase[j];
        int pl = j / 20;                 // 20 float4 per prior
        int c0 = (j - pl * 20) * 4;
        int f = flag_s[pl];
        int tc = tcls_s[pl];
        float s = 0.0f;
        {
            float fk = focal(v.x, (f == 1) && (c0 == tc));
            if (!((f == 2) && (c0 == tc))) s += fk;
        }
        {
            float fk = focal(v.y, (f == 1) && (c0 + 1 == tc));
            if (!((f == 2) && (c0 + 1 == tc))) s += fk;
        }
        {
            float fk = focal(v.z, (f == 1) && (c0 + 2 == tc));
            if (!((f == 2) && (c0 + 2 == tc))) s += fk;
        }
        {
            float fk = focal(v.w, (f == 1) && (c0 + 3 == tc));
            if (!((f == 2) && (c0 + 3 == tc))) s += fk;
        }
        sum_c += s;
    }

    // block reduce
    const int lane = tid & 63, wid = tid >> 6;
#pragma unroll
    for (int off = 32; off > 0; off >>= 1) {
        sum_l += __shfl_down(sum_l, off, 64);
        sum_c += __shfl_down(sum_c, off, 64);
        pos_c += __shfl_down(pos_c, off, 64);
        ign_c += __shfl_down(ign_c, off, 64);
    }
    if (lane == 0) { rf_l[wid] = sum_l; rf_c[wid] = sum_c; ri_p[wid] = pos_c; ri_i[wid] = ign_c; }
    __syncthreads();
    if (tid == 0) {
        float tl = rf_l[0] + rf_l[1] + rf_l[2] + rf_l[3];
        float tcs = rf_c[0] + rf_c[1] + rf_c[2] + rf_c[3];
        int tp = ri_p[0] + ri_p[1] + ri_p[2] + ri_p[3];
        int ti = ri_i[0] + ri_i[1] + ri_i[2] + ri_i[3];
        atomicAdd(&acc->sum_l, (double)tl);
        atomicAdd(&acc->sum_c, (double)tcs);
        atomicAdd(&acc->n_pos, (unsigned)tp);
        atomicAdd(&acc->n_ign, (unsigned)ti);
    }
}

// ---------------- Kernel C: finalize ----------------
__global__ void finalize_kernel(const Accums* __restrict__ acc, float* __restrict__ out) {
    if (threadIdx.x == 0 && blockIdx.x == 0) {
        double sl = acc->sum_l, sc = acc->sum_c;
        unsigned np_ = acc->n_pos, ni = acc->n_ign;
        double npos = (np_ < 1u) ? 1.0 : (double)np_;
        long long msum = (long long)B_SZ * P_SZ * C_SZ - (long long)ni;
        if (msum < 1) msum = 1;
        out[0] = (float)(sl / (4.0 * npos));
        out[1] = (float)(sc / (double)msum);
    }
}

extern "C" void kernel_launch(void* const* d_in, const int* in_sizes, int n_in,
                              void* d_out, int out_size, void* d_ws, size_t ws_size,
                              hipStream_t stream) {
    const float* loc     = (const float*)d_in[0];
    const float* conf    = (const float*)d_in[1];
    const float* priors  = (const float*)d_in[2];
    const float* targets = (const float*)d_in[3];

    unsigned long long* keys = (unsigned long long*)d_ws;
    Accums* acc = (Accums*)((char*)d_ws + 4096);

    (void)hipMemsetAsync(d_ws, 0, 4096 + sizeof(Accums), stream);
    match_kernel<<<dim3(16, 16), 256, 0, stream>>>(priors, targets, keys);
    loss_kernel<<<dim3(128, 16), 256, 0, stream>>>(loc, conf, priors, targets, keys, acc);
    finalize_kernel<<<1, 64, 0, stream>>>(acc, (float*)d_out);
}

// Round 3
// 66.141 us; speedup vs baseline: 2.2292x; 2.2292x over previous
//
#include <hip/hip_runtime.h>

#pragma clang fp contract(off)

#define B_SZ 16
#define P_SZ 16384
#define C_SZ 80
#define T_SZ 32

// ws layout:
// [0, 65536):        unsigned long long keys[16 batches][16 chunks][32 truths]
// [65536, +32768):   Partial partials[2048]
struct Partial { float l; float c; unsigned pos; unsigned ign; };

__device__ __forceinline__ float iou_ref(float ax0, float ay0, float ax1, float ay1, float aarea,
                                         float bx0, float by0, float bx1, float by1, float barea) {
    float lx = fmaxf(ax0, bx0), ly = fmaxf(ay0, by0);
    float rx = fminf(ax1, bx1), ry = fminf(ay1, by1);
    float w = fmaxf(rx - lx, 0.0f), h = fmaxf(ry - ly, 0.0f);
    float inter = w * h;
    float denom = (aarea + barea) - inter;
    return inter / denom;
}

// ---------------- Kernel A: per-truth argmax over a 1024-prior chunk ----------------
__global__ __launch_bounds__(256) void match_kernel(const float* __restrict__ priors,
                                                    const float* __restrict__ targets,
                                                    unsigned long long* __restrict__ keys) {
    const int b = blockIdx.y;
    const int p0 = blockIdx.x * 1024;
    const int tid = threadIdx.x;

    __shared__ float tx0[T_SZ], ty0[T_SZ], tx1[T_SZ], ty1[T_SZ], tar[T_SZ];
    __shared__ float red_ov[4][T_SZ];
    __shared__ int   red_ix[4][T_SZ];

    if (tid < T_SZ) {
        const float* tp = targets + (b * T_SZ + tid) * 5;
        float x0 = tp[0], y0 = tp[1], x1 = tp[2], y1 = tp[3];
        tx0[tid] = x0; ty0[tid] = y0; tx1[tid] = x1; ty1[tid] = y1;
        tar[tid] = (x1 - x0) * (y1 - y0);
    }
    __syncthreads();

    float bov[T_SZ];
    int   bpi[T_SZ];
#pragma unroll
    for (int t = 0; t < T_SZ; ++t) { bov[t] = -1.0f; bpi[t] = 0x7FFFFFFF; }

#pragma unroll
    for (int i = 0; i < 4; ++i) {
        int p = p0 + tid + i * 256;
        float4 pr = reinterpret_cast<const float4*>(priors)[p];
        float px0 = pr.x - pr.z * 0.5f, py0 = pr.y - pr.w * 0.5f;
        float px1 = pr.x + pr.z * 0.5f, py1 = pr.y + pr.w * 0.5f;
        float parea = (px1 - px0) * (py1 - py0);
#pragma unroll
        for (int t = 0; t < T_SZ; ++t) {
            float iou = iou_ref(tx0[t], ty0[t], tx1[t], ty1[t], tar[t], px0, py0, px1, py1, parea);
            if (iou > bov[t]) { bov[t] = iou; bpi[t] = p; }  // ascending p -> first-index tie-break
        }
    }

    const int lane = tid & 63, wid = tid >> 6;
#pragma unroll
    for (int t = 0; t < T_SZ; ++t) {
        float v = bov[t]; int ix = bpi[t];
#pragma unroll
        for (int off = 32; off > 0; off >>= 1) {
            float v2 = __shfl_down(v, off, 64);
            int   i2 = __shfl_down(ix, off, 64);
            if (v2 > v || (v2 == v && i2 < ix)) { v = v2; ix = i2; }
        }
        if (lane == 0) { red_ov[wid][t] = v; red_ix[wid][t] = ix; }
    }
    __syncthreads();

    if (tid < T_SZ) {
        float v = red_ov[0][tid]; int ix = red_ix[0][tid];
#pragma unroll
        for (int w = 1; w < 4; ++w) {
            float v2 = red_ov[w][tid]; int i2 = red_ix[w][tid];
            if (v2 > v || (v2 == v && i2 < ix)) { v = v2; ix = i2; }
        }
        // pack: higher iou wins; tie -> smaller prior index (via ~idx). iou >= 0 so u32 bits order ok.
        unsigned long long key = (((unsigned long long)__float_as_uint(v)) << 32)
                               | (unsigned long long)(0xFFFFFFFFu - (unsigned)ix);
        keys[(b * 16 + blockIdx.x) * T_SZ + tid] = key;   // direct store, no atomic, no pre-zero
    }
}

// ---------------- balanced L1 ----------------
__device__ __forceinline__ float bl1(float pred, float target) {
    const float bC   = (float)19.085536923187668;            // e^3 - 1
    const float aob  = (float)(0.5 / 19.085536923187668);    // alpha/b
    const float cL   = (float)(1.5 / 19.085536923187668 - 0.055); // gamma/b - alpha*beta
    float d = fabsf(pred - target);
    if (d < 0.11f) {
        return aob * (bC * d + 1.0f) * __logf(bC * d / 0.11f + 1.0f) - 0.5f * d;
    }
    return 1.5f * d + cL;
}

// ---------------- focal (t in {0,1}, gamma = 1) ----------------
__device__ __forceinline__ float focal(float x, bool isT) {
    float u  = __expf(-fabsf(x));
    float L  = __logf(1.0f + u);
    float q  = __builtin_amdgcn_rcpf(1.0f + u);
    float p  = (x >= 0.0f) ? q : 1.0f - q;   // sigmoid(x)
    float xp = fmaxf(x, 0.0f);
    float xn = xp - x;                        // max(-x, 0)
    // t=1: 0.25*(1-p)*softplus(-x) ; t=0: 0.75*p*softplus(x)
    return isT ? 0.25f * (1.0f - p) * (xn + L) : 0.75f * p * (xp + L);
}

// ---------------- Kernel B: losses ----------------
__global__ __launch_bounds__(256) void loss_kernel(const float* __restrict__ loc_data,
                                                   const float* __restrict__ conf_data,
                                                   const float* __restrict__ priors,
                                                   const float* __restrict__ targets,
                                                   const unsigned long long* __restrict__ keys,
                                                   Partial* __restrict__ partials) {
    const int b = blockIdx.y;
    const int p0 = blockIdx.x * 128;
    const int tid = threadIdx.x;

    __shared__ float tx0[T_SZ], ty0[T_SZ], tx1[T_SZ], ty1[T_SZ], tar[T_SZ];
    __shared__ int tlab[T_SZ], bp[T_SZ];
    __shared__ unsigned char flag_s[128];
    __shared__ unsigned char tcls_s[128];
    __shared__ unsigned char code_s[2560];
    __shared__ float rf_l[4], rf_c[4];
    __shared__ int ri_p[4], ri_i[4];

    if (tid < T_SZ) {
        const float* tp = targets + (b * T_SZ + tid) * 5;
        float x0 = tp[0], y0 = tp[1], x1 = tp[2], y1 = tp[3];
        tx0[tid] = x0; ty0[tid] = y0; tx1[tid] = x1; ty1[tid] = y1;
        tar[tid] = (x1 - x0) * (y1 - y0);
        tlab[tid] = (int)tp[4];
        // reduce the 16 per-chunk keys for this (b, truth)
        const unsigned long long* kb = keys + b * 16 * T_SZ + tid;
        unsigned long long k = kb[0];
#pragma unroll
        for (int w = 1; w < 16; ++w) {
            unsigned long long k2 = kb[w * T_SZ];
            if (k2 > k) k = k2;
        }
        bp[tid] = (int)(0xFFFFFFFFu - (unsigned)(k & 0xFFFFFFFFull));
    }
    __syncthreads();

    float sum_l = 0.0f, sum_c = 0.0f;
    int pos_c = 0, ign_c = 0;

    if (tid < 128) {
        int p = p0 + tid;
        float4 pr = reinterpret_cast<const float4*>(priors)[p];
        float px0 = pr.x - pr.z * 0.5f, py0 = pr.y - pr.w * 0.5f;
        float px1 = pr.x + pr.z * 0.5f, py1 = pr.y + pr.w * 0.5f;
        float parea = (px1 - px0) * (py1 - py0);

        float ov = -1.0f; int idx = 0;
#pragma unroll
        for (int t = 0; t < T_SZ; ++t) {
            float iou = iou_ref(tx0[t], ty0[t], tx1[t], ty1[t], tar[t], px0, py0, px1, py1, parea);
            if (iou > ov) { ov = iou; idx = t; }   // first-index tie-break
        }
        // override: ascending t, last write wins (matches .at[].set)
#pragma unroll
        for (int t = 0; t < T_SZ; ++t) if (bp[t] == p) { ov = 2.0f; idx = t; }

        int fl = (ov >= 0.5f) ? 1 : ((ov >= 0.4f) ? 2 : 0);
        flag_s[tid] = (unsigned char)fl;
        tcls_s[tid] = (unsigned char)tlab[idx];

        if (fl == 1) {
            pos_c = 1;
            float4 ld = reinterpret_cast<const float4*>(loc_data)[b * P_SZ + p];
            float mx0 = tx0[idx], my0 = ty0[idx], mx1 = tx1[idx], my1 = ty1[idx];
            float gx = ((mx0 + mx1) * 0.5f - pr.x) / (0.1f * pr.z);
            float gy = ((my0 + my1) * 0.5f - pr.y) / (0.1f * pr.w);
            float gw = __logf((mx1 - mx0) / pr.z) / 0.2f;
            float gh = __logf((my1 - my0) / pr.w) / 0.2f;
            sum_l = bl1(ld.x, gx) + bl1(ld.y, gy) + bl1(ld.z, gw) + bl1(ld.w, gh);
        } else if (fl == 2) {
            ign_c = 1;
        }
    }
    __syncthreads();

    // build per-float4 code table: code = flag | (match_slot << 2); match_slot 0=none, 1..4 = lane in float4
#pragma unroll
    for (int jj = tid; jj < 2560; jj += 256) {
        int pl = jj / 20;
        int c0 = (jj - pl * 20) * 4;
        int f = flag_s[pl];
        int tc = tcls_s[pl];
        int g = tc - c0;
        int m = (g >= 0 && g < 4) ? (g + 1) : 0;
        code_s[jj] = (unsigned char)(f | (m << 2));
    }
    __syncthreads();

    // conf stream: 128 priors * 80 ch = 2560 float4; all 10 loads issued up-front for MLP
    const float4* cbase = reinterpret_cast<const float4*>(conf_data + ((size_t)(b * P_SZ + p0)) * C_SZ);
    float4 v[10];
#pragma unroll
    for (int it = 0; it < 10; ++it) v[it] = cbase[tid + it * 256];
    unsigned char cd[10];
#pragma unroll
    for (int it = 0; it < 10; ++it) cd[it] = code_s[tid + it * 256];

#pragma unroll
    for (int it = 0; it < 10; ++it) {
        int code = cd[it];
        int f = code & 3;
        int m = code >> 2;
        float s = 0.0f;
        {
            float fk = focal(v[it].x, (f == 1) && (m == 1));
            if (!((f == 2) && (m == 1))) s += fk;
        }
        {
            float fk = focal(v[it].y, (f == 1) && (m == 2));
            if (!((f == 2) && (m == 2))) s += fk;
        }
        {
            float fk = focal(v[it].z, (f == 1) && (m == 3));
            if (!((f == 2) && (m == 3))) s += fk;
        }
        {
            float fk = focal(v[it].w, (f == 1) && (m == 4));
            if (!((f == 2) && (m == 4))) s += fk;
        }
        sum_c += s;
    }

    // block reduce
    const int lane = tid & 63, wid = tid >> 6;
#pragma unroll
    for (int off = 32; off > 0; off >>= 1) {
        sum_l += __shfl_down(sum_l, off, 64);
        sum_c += __shfl_down(sum_c, off, 64);
        pos_c += __shfl_down(pos_c, off, 64);
        ign_c += __shfl_down(ign_c, off, 64);
    }
    if (lane == 0) { rf_l[wid] = sum_l; rf_c[wid] = sum_c; ri_p[wid] = pos_c; ri_i[wid] = ign_c; }
    __syncthreads();
    if (tid == 0) {
        Partial pt;
        pt.l = rf_l[0] + rf_l[1] + rf_l[2] + rf_l[3];
        pt.c = rf_c[0] + rf_c[1] + rf_c[2] + rf_c[3];
        pt.pos = (unsigned)(ri_p[0] + ri_p[1] + ri_p[2] + ri_p[3]);
        pt.ign = (unsigned)(ri_i[0] + ri_i[1] + ri_i[2] + ri_i[3]);
        partials[b * 128 + blockIdx.x] = pt;   // 16B store, no atomics
    }
}

// ---------------- Kernel C: finalize (deterministic tree reduce of 2048 partials) ----------------
__global__ __launch_bounds__(256) void finalize_kernel(const Partial* __restrict__ partials,
                                                       float* __restrict__ out) {
    const int tid = threadIdx.x;
    __shared__ double r_l[4], r_c[4];
    __shared__ unsigned long long r_p[4], r_i[4];

    double sl = 0.0, sc = 0.0;
    unsigned long long np = 0, ni = 0;
#pragma unroll
    for (int k = 0; k < 8; ++k) {
        Partial p = partials[tid + k * 256];
        sl += (double)p.l; sc += (double)p.c;
        np += p.pos; ni += p.ign;
    }
    const int lane = tid & 63, wid = tid >> 6;
#pragma unroll
    for (int off = 32; off > 0; off >>= 1) {
        sl += __shfl_down(sl, off, 64);
        sc += __shfl_down(sc, off, 64);
        np += __shfl_down(np, off, 64);
        ni += __shfl_down(ni, off, 64);
    }
    if (lane == 0) { r_l[wid] = sl; r_c[wid] = sc; r_p[wid] = np; r_i[wid] = ni; }
    __syncthreads();
    if (tid == 0) {
        double tl = r_l[0] + r_l[1] + r_l[2] + r_l[3];
        double tc = r_c[0] + r_c[1] + r_c[2] + r_c[3];
        unsigned long long tp = r_p[0] + r_p[1] + r_p[2] + r_p[3];
        long long ti = (long long)(r_i[0] + r_i[1] + r_i[2] + r_i[3]);
        double npos = (tp < 1ull) ? 1.0 : (double)tp;
        long long msum = (long long)B_SZ * P_SZ * C_SZ - ti;
        if (msum < 1) msum = 1;
        out[0] = (float)(tl / (4.0 * npos));
        out[1] = (float)(tc / (double)msum);
    }
}

extern "C" void kernel_launch(void* const* d_in, const int* in_sizes, int n_in,
                              void* d_out, int out_size, void* d_ws, size_t ws_size,
                              hipStream_t stream) {
    const float* loc     = (const float*)d_in[0];
    const float* conf    = (const float*)d_in[1];
    const float* priors  = (const float*)d_in[2];
    const float* targets = (const float*)d_in[3];

    unsigned long long* keys = (unsigned long long*)d_ws;
    Partial* partials = (Partial*)((char*)d_ws + 65536);

    match_kernel<<<dim3(16, 16), 256, 0, stream>>>(priors, targets, keys);
    loss_kernel<<<dim3(128, 16), 256, 0, stream>>>(loc, conf, priors, targets, keys, partials);
    finalize_kernel<<<1, 256, 0, stream>>>(partials, (float*)d_out);
}

// Round 4
// 65.478 us; speedup vs baseline: 2.2517x; 1.0101x over previous
//
#include <hip/hip_runtime.h>

#pragma clang fp contract(off)

#define B_SZ 16
#define P_SZ 16384
#define C_SZ 80
#define T_SZ 32
#define NCHUNK 32   // match chunks (512 priors each)

// ws layout (bytes):
// [0, 131072):           u64 keys[16][32][32]
// [131072, 655360):      ushort codes[16][16384]   (class<<2 | flag)
// [655360, 671744):      PartialL pl[1024]
// [671744, 679936):      float pc[2048]
struct PartialL { float l; float pad; unsigned pos; unsigned ign; };

__device__ __forceinline__ float iou_ref(float ax0, float ay0, float ax1, float ay1, float aarea,
                                         float bx0, float by0, float bx1, float by1, float barea) {
    float lx = fmaxf(ax0, bx0), ly = fmaxf(ay0, by0);
    float rx = fminf(ax1, bx1), ry = fminf(ay1, by1);
    float w = fmaxf(rx - lx, 0.0f), h = fmaxf(ry - ly, 0.0f);
    float inter = w * h;
    float denom = (aarea + barea) - inter;
    return inter / denom;
}

// ---------------- K1: per-truth argmax over a 512-prior chunk ----------------
__global__ __launch_bounds__(256) void match_kernel(const float* __restrict__ priors,
                                                    const float* __restrict__ targets,
                                                    unsigned long long* __restrict__ keys) {
    const int b = blockIdx.y;
    const int p0 = blockIdx.x * 512;
    const int tid = threadIdx.x;

    __shared__ float tx0[T_SZ], ty0[T_SZ], tx1[T_SZ], ty1[T_SZ], tar[T_SZ];
    __shared__ float red_ov[4][T_SZ];
    __shared__ int   red_ix[4][T_SZ];

    if (tid < T_SZ) {
        const float* tp = targets + (b * T_SZ + tid) * 5;
        float x0 = tp[0], y0 = tp[1], x1 = tp[2], y1 = tp[3];
        tx0[tid] = x0; ty0[tid] = y0; tx1[tid] = x1; ty1[tid] = y1;
        tar[tid] = (x1 - x0) * (y1 - y0);
    }
    __syncthreads();

    float bov[T_SZ];
    int   bpi[T_SZ];
#pragma unroll
    for (int t = 0; t < T_SZ; ++t) { bov[t] = -1.0f; bpi[t] = 0x7FFFFFFF; }

#pragma unroll
    for (int i = 0; i < 2; ++i) {
        int p = p0 + tid + i * 256;
        float4 pr = reinterpret_cast<const float4*>(priors)[p];
        float px0 = pr.x - pr.z * 0.5f, py0 = pr.y - pr.w * 0.5f;
        float px1 = pr.x + pr.z * 0.5f, py1 = pr.y + pr.w * 0.5f;
        float parea = (px1 - px0) * (py1 - py0);
#pragma unroll
        for (int t = 0; t < T_SZ; ++t) {
            float iou = iou_ref(tx0[t], ty0[t], tx1[t], ty1[t], tar[t], px0, py0, px1, py1, parea);
            if (iou > bov[t]) { bov[t] = iou; bpi[t] = p; }  // ascending p -> first-index tie-break
        }
    }

    const int lane = tid & 63, wid = tid >> 6;
#pragma unroll
    for (int t = 0; t < T_SZ; ++t) {
        float v = bov[t]; int ix = bpi[t];
#pragma unroll
        for (int off = 32; off > 0; off >>= 1) {
            float v2 = __shfl_down(v, off, 64);
            int   i2 = __shfl_down(ix, off, 64);
            if (v2 > v || (v2 == v && i2 < ix)) { v = v2; ix = i2; }
        }
        if (lane == 0) { red_ov[wid][t] = v; red_ix[wid][t] = ix; }
    }
    __syncthreads();

    if (tid < T_SZ) {
        float v = red_ov[0][tid]; int ix = red_ix[0][tid];
#pragma unroll
        for (int w = 1; w < 4; ++w) {
            float v2 = red_ov[w][tid]; int i2 = red_ix[w][tid];
            if (v2 > v || (v2 == v && i2 < ix)) { v = v2; ix = i2; }
        }
        unsigned long long key = (((unsigned long long)__float_as_uint(v)) << 32)
                               | (unsigned long long)(0xFFFFFFFFu - (unsigned)ix);
        keys[(b * NCHUNK + blockIdx.x) * T_SZ + tid] = key;
    }
}

// ---------------- balanced L1 ----------------
__device__ __forceinline__ float bl1(float pred, float target) {
    const float bC   = (float)19.085536923187668;
    const float aob  = (float)(0.5 / 19.085536923187668);
    const float cL   = (float)(1.5 / 19.085536923187668 - 0.055);
    float d = fabsf(pred - target);
    if (d < 0.11f) {
        return aob * (bC * d + 1.0f) * __logf(bC * d / 0.11f + 1.0f) - 0.5f * d;
    }
    return 1.5f * d + cL;
}

// ---------------- focal (t in {0,1}, gamma = 1) ----------------
__device__ __forceinline__ float focal(float x, bool isT) {
    float u  = __expf(-fabsf(x));
    float L  = __logf(1.0f + u);
    float q  = __builtin_amdgcn_rcpf(1.0f + u);
    float p  = (x >= 0.0f) ? q : 1.0f - q;
    float xp = fmaxf(x, 0.0f);
    float xn = xp - x;
    return isT ? 0.25f * (1.0f - p) * (xn + L) : 0.75f * p * (xp + L);
}

// ---------------- K2: per-prior flag/class + loc loss ----------------
__global__ __launch_bounds__(256) void flags_kernel(const float* __restrict__ loc_data,
                                                    const float* __restrict__ priors,
                                                    const float* __restrict__ targets,
                                                    const unsigned long long* __restrict__ keys,
                                                    unsigned short* __restrict__ codes,
                                                    PartialL* __restrict__ pl_out) {
    const int b = blockIdx.y;
    const int p0 = blockIdx.x * 256;
    const int tid = threadIdx.x;
    const int p = p0 + tid;

    __shared__ float tx0[T_SZ], ty0[T_SZ], tx1[T_SZ], ty1[T_SZ], tar[T_SZ];
    __shared__ int tlab[T_SZ], bp[T_SZ];
    __shared__ float rf[4];
    __shared__ int rp[4], ri[4];

    if (tid < T_SZ) {
        const float* tp = targets + (b * T_SZ + tid) * 5;
        float x0 = tp[0], y0 = tp[1], x1 = tp[2], y1 = tp[3];
        tx0[tid] = x0; ty0[tid] = y0; tx1[tid] = x1; ty1[tid] = y1;
        tar[tid] = (x1 - x0) * (y1 - y0);
        tlab[tid] = (int)tp[4];
        const unsigned long long* kb = keys + b * (NCHUNK * T_SZ) + tid;
        unsigned long long k = kb[0];
#pragma unroll
        for (int w = 1; w < NCHUNK; ++w) {
            unsigned long long k2 = kb[w * T_SZ];
            if (k2 > k) k = k2;
        }
        bp[tid] = (int)(0xFFFFFFFFu - (unsigned)(k & 0xFFFFFFFFull));
    }
    __syncthreads();

    float4 pr = reinterpret_cast<const float4*>(priors)[p];
    float px0 = pr.x - pr.z * 0.5f, py0 = pr.y - pr.w * 0.5f;
    float px1 = pr.x + pr.z * 0.5f, py1 = pr.y + pr.w * 0.5f;
    float parea = (px1 - px0) * (py1 - py0);

    float ov = -1.0f; int idx = 0;
#pragma unroll
    for (int t = 0; t < T_SZ; ++t) {
        float iou = iou_ref(tx0[t], ty0[t], tx1[t], ty1[t], tar[t], px0, py0, px1, py1, parea);
        if (iou > ov) { ov = iou; idx = t; }
    }
#pragma unroll
    for (int t = 0; t < T_SZ; ++t) if (bp[t] == p) { ov = 2.0f; idx = t; }

    int fl = (ov >= 0.5f) ? 1 : ((ov >= 0.4f) ? 2 : 0);
    int tc = tlab[idx];
    codes[b * P_SZ + p] = (unsigned short)((tc << 2) | fl);

    float sum_l = 0.0f;
    int pos_c = 0, ign_c = 0;
    if (fl == 1) {
        pos_c = 1;
        float4 ld = reinterpret_cast<const float4*>(loc_data)[b * P_SZ + p];
        float mx0 = tx0[idx], my0 = ty0[idx], mx1 = tx1[idx], my1 = ty1[idx];
        float gx = ((mx0 + mx1) * 0.5f - pr.x) / (0.1f * pr.z);
        float gy = ((my0 + my1) * 0.5f - pr.y) / (0.1f * pr.w);
        float gw = __logf((mx1 - mx0) / pr.z) / 0.2f;
        float gh = __logf((my1 - my0) / pr.w) / 0.2f;
        sum_l = bl1(ld.x, gx) + bl1(ld.y, gy) + bl1(ld.z, gw) + bl1(ld.w, gh);
    } else if (fl == 2) {
        ign_c = 1;
    }

    const int lane = tid & 63, wid = tid >> 6;
#pragma unroll
    for (int off = 32; off > 0; off >>= 1) {
        sum_l += __shfl_down(sum_l, off, 64);
        pos_c += __shfl_down(pos_c, off, 64);
        ign_c += __shfl_down(ign_c, off, 64);
    }
    if (lane == 0) { rf[wid] = sum_l; rp[wid] = pos_c; ri[wid] = ign_c; }
    __syncthreads();
    if (tid == 0) {
        PartialL o;
        o.l = rf[0] + rf[1] + rf[2] + rf[3];
        o.pad = 0.0f;
        o.pos = (unsigned)(rp[0] + rp[1] + rp[2] + rp[3]);
        o.ign = (unsigned)(ri[0] + ri[1] + ri[2] + ri[3]);
        pl_out[b * 64 + blockIdx.x] = o;
    }
}

// ---------------- K3: conf stream (barrier-free) ----------------
__global__ __launch_bounds__(256) void conf_kernel(const float* __restrict__ conf_data,
                                                   const unsigned short* __restrict__ codes,
                                                   float* __restrict__ pc_out) {
    const int b = blockIdx.y;
    const int p0 = blockIdx.x * 128;
    const int tid = threadIdx.x;

    const float4* cbase = reinterpret_cast<const float4*>(conf_data + ((size_t)(b * P_SZ + p0)) * C_SZ);
    const unsigned short* cdb = codes + b * P_SZ + p0;

    float4 v[10];
    unsigned short cd[10];
#pragma unroll
    for (int it = 0; it < 10; ++it) {
        int j = tid + it * 256;
        v[it] = cbase[j];
        cd[it] = cdb[j / 20];
    }

    float sum_c = 0.0f;
#pragma unroll
    for (int it = 0; it < 10; ++it) {
        int j = tid + it * 256;
        int pl = j / 20;
        int c0 = (j - pl * 20) * 4;
        int f = cd[it] & 3;
        int g = (cd[it] >> 2) - c0;   // matched-slot relative to this float4
        float s = 0.0f;
        {
            float fk = focal(v[it].x, (f == 1) && (g == 0));
            if (!((f == 2) && (g == 0))) s += fk;
        }
        {
            float fk = focal(v[it].y, (f == 1) && (g == 1));
            if (!((f == 2) && (g == 1))) s += fk;
        }
        {
            float fk = focal(v[it].z, (f == 1) && (g == 2));
            if (!((f == 2) && (g == 2))) s += fk;
        }
        {
            float fk = focal(v[it].w, (f == 1) && (g == 3));
            if (!((f == 2) && (g == 3))) s += fk;
        }
        sum_c += s;
    }

    __shared__ float rf[4];
    const int lane = tid & 63, wid = tid >> 6;
#pragma unroll
    for (int off = 32; off > 0; off >>= 1) sum_c += __shfl_down(sum_c, off, 64);
    if (lane == 0) rf[wid] = sum_c;
    __syncthreads();
    if (tid == 0) pc_out[b * 128 + blockIdx.x] = rf[0] + rf[1] + rf[2] + rf[3];
}

// ---------------- K4: finalize ----------------
__global__ __launch_bounds__(256) void finalize_kernel(const PartialL* __restrict__ pl,
                                                       const float* __restrict__ pc,
                                                       float* __restrict__ out) {
    const int tid = threadIdx.x;
    __shared__ double r_l[4], r_c[4];
    __shared__ unsigned long long r_p[4], r_i[4];

    double sl = 0.0, sc = 0.0;
    unsigned long long np = 0, ni = 0;
#pragma unroll
    for (int k = 0; k < 4; ++k) {
        PartialL p = pl[tid + k * 256];
        sl += (double)p.l; np += p.pos; ni += p.ign;
    }
#pragma unroll
    for (int k = 0; k < 8; ++k) sc += (double)pc[tid + k * 256];

    const int lane = tid & 63, wid = tid >> 6;
#pragma unroll
    for (int off = 32; off > 0; off >>= 1) {
        sl += __shfl_down(sl, off, 64);
        sc += __shfl_down(sc, off, 64);
        np += __shfl_down(np, off, 64);
        ni += __shfl_down(ni, off, 64);
    }
    if (lane == 0) { r_l[wid] = sl; r_c[wid] = sc; r_p[wid] = np; r_i[wid] = ni; }
    __syncthreads();
    if (tid == 0) {
        double tl = r_l[0] + r_l[1] + r_l[2] + r_l[3];
        double tc = r_c[0] + r_c[1] + r_c[2] + r_c[3];
        unsigned long long tp = r_p[0] + r_p[1] + r_p[2] + r_p[3];
        long long ti = (long long)(r_i[0] + r_i[1] + r_i[2] + r_i[3]);
        double npos = (tp < 1ull) ? 1.0 : (double)tp;
        long long msum = (long long)B_SZ * P_SZ * C_SZ - ti;
        if (msum < 1) msum = 1;
        out[0] = (float)(tl / (4.0 * npos));
        out[1] = (float)(tc / (double)msum);
    }
}

extern "C" void kernel_launch(void* const* d_in, const int* in_sizes, int n_in,
                              void* d_out, int out_size, void* d_ws, size_t ws_size,
                              hipStream_t stream) {
    const float* loc     = (const float*)d_in[0];
    const float* conf    = (const float*)d_in[1];
    const float* priors  = (const float*)d_in[2];
    const float* targets = (const float*)d_in[3];

    char* ws = (char*)d_ws;
    unsigned long long* keys = (unsigned long long*)ws;                 // 131072 B
    unsigned short*    codes = (unsigned short*)(ws + 131072);          // 524288 B
    PartialL*          plp   = (PartialL*)(ws + 655360);                // 16384 B
    float*             pcp   = (float*)(ws + 671744);                   // 8192 B

    match_kernel<<<dim3(NCHUNK, 16), 256, 0, stream>>>(priors, targets, keys);
    flags_kernel<<<dim3(64, 16), 256, 0, stream>>>(loc, priors, targets, keys, codes, plp);
    conf_kernel<<<dim3(128, 16), 256, 0, stream>>>(conf, codes, pcp);
    finalize_kernel<<<1, 256, 0, stream>>>(plp, pcp, (float*)d_out);
}